// Round 6
// baseline (527.186 us; speedup 1.0000x reference)
//
#include <hip/hip_runtime.h>

// GCN link predictor, fp32 — round 6:
//  * W matrices read from global (L1-broadcast) instead of LDS staging:
//    mlp LDS 53.7->21KB (2->7 blocks/CU), gemm<128> 66->34KB (2->4 blocks/CU)
//  * aggregate: 4-way unrolled accumulators (2x memory-level parallelism)
//  * deg_kernel: int4 edge loads
//
// ws layout (float units):
//   0        norm_src [N]
//   100000   norm_dst [N]
//   200000   deg_out / cursor (int) [N]
//   300000   deg_in (int) [N]
//   400000   row_ptr (int) [N+1]
//   500004   cedge (float4) [E]          (src, w_l0, w_l1, w_l2) per edge
//   4500004  hw   [N*64]   (scan scratch before layer 0)
//   10900004 agg  [N*64]
// total 17300004 floats = 69.2 MB

#define NN 100000
#define NE 1000000
#define NP 100000
#define SCAN_NB 98

__device__ __forceinline__ void row_fma(float4& acc, float xv, const float4& wv) {
    acc.x = fmaf(xv, wv.x, acc.x);
    acc.y = fmaf(xv, wv.y, acc.y);
    acc.z = fmaf(xv, wv.z, acc.z);
    acc.w = fmaf(xv, wv.w, acc.w);
}

__global__ void deg_kernel(const int4* __restrict__ src4, const int4* __restrict__ dst4,
                           int* __restrict__ deg_out, int* __restrict__ deg_in, int E4) {
    int tid = blockIdx.x * blockDim.x + threadIdx.x;
    if (tid < E4) {
        int4 s = src4[tid], d = dst4[tid];
        atomicAdd(&deg_out[s.x], 1);
        atomicAdd(&deg_out[s.y], 1);
        atomicAdd(&deg_out[s.z], 1);
        atomicAdd(&deg_out[s.w], 1);
        atomicAdd(&deg_in[d.x], 1);
        atomicAdd(&deg_in[d.y], 1);
        atomicAdd(&deg_in[d.z], 1);
        atomicAdd(&deg_in[d.w], 1);
    }
}

__global__ void norm_kernel(const int* __restrict__ deg_out, const int* __restrict__ deg_in,
                            float* __restrict__ norm_src, float* __restrict__ norm_dst, int n) {
    int i = blockIdx.x * blockDim.x + threadIdx.x;
    if (i < n) {
        norm_src[i] = rsqrtf(fmaxf((float)deg_out[i], 1.0f));
        norm_dst[i] = rsqrtf(fmaxf((float)deg_in[i], 1.0f));
    }
}

__global__ __launch_bounds__(1024) void scan_block(const int* __restrict__ deg,
                                                   int* __restrict__ tmp_excl,
                                                   int* __restrict__ blocksums, int n) {
    __shared__ int wsums[16];
    const int i = blockIdx.x * 1024 + threadIdx.x;
    const int lane = threadIdx.x & 63, w = threadIdx.x >> 6;
    int v = (i < n) ? deg[i] : 0;
    int s = v;
#pragma unroll
    for (int off = 1; off < 64; off <<= 1) {
        int u = __shfl_up(s, off, 64);
        if (lane >= off) s += u;
    }
    if (lane == 63) wsums[w] = s;
    __syncthreads();
    if (w == 0) {
        int wv = (lane < 16) ? wsums[lane] : 0;
#pragma unroll
        for (int off = 1; off < 16; off <<= 1) {
            int u = __shfl_up(wv, off, 64);
            if (lane >= off) wv += u;
        }
        if (lane < 16) wsums[lane] = wv;
    }
    __syncthreads();
    int excl = s - v + (w > 0 ? wsums[w - 1] : 0);
    if (i < n) tmp_excl[i] = excl;
    if (threadIdx.x == 1023) blocksums[blockIdx.x] = excl + v;
}

__global__ void scan_sums(int* __restrict__ bs, int nb) {
    __shared__ int wtot[2];
    const int t = threadIdx.x;  // 128 threads
    const int lane = t & 63, w = t >> 6;
    int v = (t < nb) ? bs[t] : 0;
    int s = v;
#pragma unroll
    for (int off = 1; off < 64; off <<= 1) {
        int u = __shfl_up(s, off, 64);
        if (lane >= off) s += u;
    }
    if (lane == 63) wtot[w] = s;
    __syncthreads();
    int excl = s - v + (w == 1 ? wtot[0] : 0);
    if (t < nb) bs[t] = excl;
}

__global__ __launch_bounds__(1024) void scan_apply(const int* __restrict__ tmp_excl,
                                                   const int* __restrict__ bs,
                                                   int* __restrict__ row_ptr,
                                                   int* __restrict__ cursor, int n) {
    const int i = blockIdx.x * 1024 + threadIdx.x;
    if (i < n) {
        int r = tmp_excl[i] + bs[blockIdx.x];
        row_ptr[i] = r;
        cursor[i] = r;
    }
    if (i == 0) row_ptr[n] = NE;
}

// pack each edge into its dst row: one scattered 16B write per edge.
__global__ void csr_fill(const int* __restrict__ src, const int* __restrict__ dst,
                         const float* __restrict__ ew, int* __restrict__ cursor,
                         float4* __restrict__ cedge, int E) {
    int tid = blockIdx.x * blockDim.x + threadIdx.x;
    int stride = gridDim.x * blockDim.x;
    for (int e = tid; e < E; e += stride) {
        int d = dst[e];
        int slot = atomicAdd(&cursor[d], 1);
        float4 c;
        c.x = __int_as_float(src[e]);
        c.y = ew[e];
        c.z = ew[NE + e];
        c.w = ew[2 * NE + e];
        cedge[slot] = c;
    }
}

// CSR pull aggregation, one wave per dst node, 4-way unrolled. Fused epilogue:
//  FINAL=0: out = relu(a*norm_dst + bias)*norm_src   (input for next pure GEMM)
//  FINAL=1: out = a*norm_dst + bias                  (b2; final conv output, no relu)
template <int WSEL, bool FINAL>
__global__ __launch_bounds__(256) void aggregate(const float* __restrict__ hw,
                                                 const float4* __restrict__ cedge,
                                                 const int* __restrict__ row_ptr,
                                                 const float* __restrict__ norm_src,
                                                 const float* __restrict__ norm_dst,
                                                 const float* __restrict__ bias,
                                                 float* __restrict__ outx, int n) {
    const int lane = threadIdx.x & 63;
    const int gw = (blockIdx.x * blockDim.x + threadIdx.x) >> 6;
    const int nw = (gridDim.x * blockDim.x) >> 6;
    const float blane = bias[lane];
    for (int node = gw; node < n; node += nw) {
        int beg = row_ptr[node], end = row_ptr[node + 1];
        float a0 = 0.f, a1 = 0.f, a2 = 0.f, a3 = 0.f;
        int i = beg;
        for (; i + 3 < end; i += 4) {
            float4 c0 = cedge[i], c1 = cedge[i + 1], c2 = cedge[i + 2], c3 = cedge[i + 3];
            int s0 = __float_as_int(c0.x), s1 = __float_as_int(c1.x);
            int s2 = __float_as_int(c2.x), s3 = __float_as_int(c3.x);
            float w0 = (WSEL == 0) ? c0.y : (WSEL == 1) ? c0.z : c0.w;
            float w1 = (WSEL == 0) ? c1.y : (WSEL == 1) ? c1.z : c1.w;
            float w2 = (WSEL == 0) ? c2.y : (WSEL == 1) ? c2.z : c2.w;
            float w3 = (WSEL == 0) ? c3.y : (WSEL == 1) ? c3.z : c3.w;
            a0 = fmaf(hw[s0 * 64 + lane], w0, a0);
            a1 = fmaf(hw[s1 * 64 + lane], w1, a1);
            a2 = fmaf(hw[s2 * 64 + lane], w2, a2);
            a3 = fmaf(hw[s3 * 64 + lane], w3, a3);
        }
        for (; i < end; ++i) {
            float4 c0 = cedge[i];
            int s0 = __float_as_int(c0.x);
            float w0 = (WSEL == 0) ? c0.y : (WSEL == 1) ? c0.z : c0.w;
            a0 = fmaf(hw[s0 * 64 + lane], w0, a0);
        }
        float a = (a0 + a1) + (a2 + a3);
        float nd = norm_dst[node];
        float t;
        if (FINAL) {
            t = fmaf(a, nd, blane);
        } else {
            t = fmaxf(fmaf(a, nd, blane), 0.f) * norm_src[node];
        }
        outx[node * 64 + lane] = t;
    }
}

// pure 64-row GEMM tile, W read from global (L1-broadcast):
// out[row][j] = (SCALE ? norm_src[row] : 1) * sum_k in[row][k]*W[k][j]
template <int K, bool SCALE>
__global__ __launch_bounds__(256) void gemm_tile(const float* __restrict__ in,
                                                 const float* __restrict__ W,
                                                 const float* __restrict__ norm_src,
                                                 float* __restrict__ out, int n) {
    __shared__ float Xs[64][K + 4];
    const int tid = threadIdx.x;
    const int ntiles = (n + 63) >> 6;
    const int tr = tid >> 4, tc = tid & 15;

    for (int tile = blockIdx.x; tile < ntiles; tile += gridDim.x) {
        for (int idx = tid; idx < K * 16; idx += 256) {
            int r = idx / (K / 4), kq = idx % (K / 4);
            int row = tile * 64 + r;
            float4 v = make_float4(0.f, 0.f, 0.f, 0.f);
            if (row < n) v = *(const float4*)&in[row * K + kq * 4];
            *(float4*)&Xs[r][kq * 4] = v;
        }
        __syncthreads();

        float4 acc0 = {0, 0, 0, 0}, acc1 = {0, 0, 0, 0}, acc2 = {0, 0, 0, 0}, acc3 = {0, 0, 0, 0};
#pragma unroll 4
        for (int k4 = 0; k4 < K / 4; ++k4) {
            const int kb = k4 * 4;
            float4 xv0 = *(const float4*)&Xs[tr * 4 + 0][kb];
            float4 xv1 = *(const float4*)&Xs[tr * 4 + 1][kb];
            float4 xv2 = *(const float4*)&Xs[tr * 4 + 2][kb];
            float4 xv3 = *(const float4*)&Xs[tr * 4 + 3][kb];
            const float* wb = &W[kb * 64 + tc * 4];
            float4 wk;
            wk = *(const float4*)(wb);
            row_fma(acc0, xv0.x, wk); row_fma(acc1, xv1.x, wk); row_fma(acc2, xv2.x, wk); row_fma(acc3, xv3.x, wk);
            wk = *(const float4*)(wb + 64);
            row_fma(acc0, xv0.y, wk); row_fma(acc1, xv1.y, wk); row_fma(acc2, xv2.y, wk); row_fma(acc3, xv3.y, wk);
            wk = *(const float4*)(wb + 128);
            row_fma(acc0, xv0.z, wk); row_fma(acc1, xv1.z, wk); row_fma(acc2, xv2.z, wk); row_fma(acc3, xv3.z, wk);
            wk = *(const float4*)(wb + 192);
            row_fma(acc0, xv0.w, wk); row_fma(acc1, xv1.w, wk); row_fma(acc2, xv2.w, wk); row_fma(acc3, xv3.w, wk);
        }

#pragma unroll
        for (int i = 0; i < 4; ++i) {
            int row = tile * 64 + tr * 4 + i;
            if (row < n) {
                float4 o = (i == 0) ? acc0 : (i == 1) ? acc1 : (i == 2) ? acc2 : acc3;
                if (SCALE) {
                    float ns = norm_src[row];
                    o.x *= ns; o.y *= ns; o.z *= ns; o.w *= ns;
                }
                *(float4*)&out[row * 64 + tc * 4] = o;
            }
        }
        __syncthreads();
    }
}

#define ZST 76  // Zs row stride

// 64 pairs/tile MLP; P0/P1 read from global (L1-broadcast), only Zs in LDS.
__global__ __launch_bounds__(256) void mlp_tile(const float* __restrict__ hfin,
                                                const float* __restrict__ P0,
                                                const float* __restrict__ pb0,
                                                const float* __restrict__ P1,
                                                const float* __restrict__ pb1,
                                                const float* __restrict__ P2,
                                                const float* __restrict__ pb2,
                                                const int* __restrict__ pos_src,
                                                const int* __restrict__ pos_dst,
                                                const int* __restrict__ neg_src,
                                                const int* __restrict__ neg_dst,
                                                float* __restrict__ out, int P) {
    __shared__ float Zs[64][ZST];
    __shared__ float pb0s[64], pb1s[64], P2s[64];
    __shared__ int pas[64], pbs[64];
    const int tid = threadIdx.x;
    if (tid < 64) {
        pb0s[tid] = pb0[tid];
        pb1s[tid] = pb1[tid];
        P2s[tid] = P2[tid];
    }
    const float pb2v = pb2[0];
    const int lane = tid & 63, w = tid >> 6;
    const int tr = tid >> 4, tc = tid & 15;
    const int ntiles = (2 * P) >> 6;  // 3125

    for (int tile = blockIdx.x; tile < ntiles; tile += gridDim.x) {
        const int base = tile << 6;
        __syncthreads();
        if (tid < 64) {
            int p = base + tid;
            pas[tid] = (p < P) ? pos_src[p] : neg_src[p - P];
            pbs[tid] = (p < P) ? pos_dst[p] : neg_dst[p - P];
        }
        __syncthreads();

#pragma unroll 4
        for (int pi = w; pi < 64; pi += 4) {
            float ha = hfin[pas[pi] * 64 + lane];
            float hb = hfin[pbs[pi] * 64 + lane];
            Zs[pi][lane] = ha * hb;
        }
        __syncthreads();

        // layer 0: Z1 = relu(Z @ P0 + pb0)
        float4 acc0, acc1, acc2, acc3;
        {
            float4 binit = *(const float4*)&pb0s[tc * 4];
            acc0 = binit; acc1 = binit; acc2 = binit; acc3 = binit;
        }
#pragma unroll 4
        for (int k4 = 0; k4 < 16; ++k4) {
            const int kb = k4 * 4;
            float4 xv0 = *(const float4*)&Zs[tr * 4 + 0][kb];
            float4 xv1 = *(const float4*)&Zs[tr * 4 + 1][kb];
            float4 xv2 = *(const float4*)&Zs[tr * 4 + 2][kb];
            float4 xv3 = *(const float4*)&Zs[tr * 4 + 3][kb];
            const float* wb = &P0[kb * 64 + tc * 4];
            float4 wk;
            wk = *(const float4*)(wb);
            row_fma(acc0, xv0.x, wk); row_fma(acc1, xv1.x, wk); row_fma(acc2, xv2.x, wk); row_fma(acc3, xv3.x, wk);
            wk = *(const float4*)(wb + 64);
            row_fma(acc0, xv0.y, wk); row_fma(acc1, xv1.y, wk); row_fma(acc2, xv2.y, wk); row_fma(acc3, xv3.y, wk);
            wk = *(const float4*)(wb + 128);
            row_fma(acc0, xv0.z, wk); row_fma(acc1, xv1.z, wk); row_fma(acc2, xv2.z, wk); row_fma(acc3, xv3.z, wk);
            wk = *(const float4*)(wb + 192);
            row_fma(acc0, xv0.w, wk); row_fma(acc1, xv1.w, wk); row_fma(acc2, xv2.w, wk); row_fma(acc3, xv3.w, wk);
        }
        __syncthreads();
#pragma unroll
        for (int i = 0; i < 4; ++i) {
            float4 o = (i == 0) ? acc0 : (i == 1) ? acc1 : (i == 2) ? acc2 : acc3;
            o.x = fmaxf(o.x, 0.f); o.y = fmaxf(o.y, 0.f); o.z = fmaxf(o.z, 0.f); o.w = fmaxf(o.w, 0.f);
            *(float4*)&Zs[tr * 4 + i][tc * 4] = o;
        }
        __syncthreads();

        // layer 1: Z2 = relu(Z1 @ P1 + pb1)
        {
            float4 binit = *(const float4*)&pb1s[tc * 4];
            acc0 = binit; acc1 = binit; acc2 = binit; acc3 = binit;
        }
#pragma unroll 4
        for (int k4 = 0; k4 < 16; ++k4) {
            const int kb = k4 * 4;
            float4 xv0 = *(const float4*)&Zs[tr * 4 + 0][kb];
            float4 xv1 = *(const float4*)&Zs[tr * 4 + 1][kb];
            float4 xv2 = *(const float4*)&Zs[tr * 4 + 2][kb];
            float4 xv3 = *(const float4*)&Zs[tr * 4 + 3][kb];
            const float* wb = &P1[kb * 64 + tc * 4];
            float4 wk;
            wk = *(const float4*)(wb);
            row_fma(acc0, xv0.x, wk); row_fma(acc1, xv1.x, wk); row_fma(acc2, xv2.x, wk); row_fma(acc3, xv3.x, wk);
            wk = *(const float4*)(wb + 64);
            row_fma(acc0, xv0.y, wk); row_fma(acc1, xv1.y, wk); row_fma(acc2, xv2.y, wk); row_fma(acc3, xv3.y, wk);
            wk = *(const float4*)(wb + 128);
            row_fma(acc0, xv0.z, wk); row_fma(acc1, xv1.z, wk); row_fma(acc2, xv2.z, wk); row_fma(acc3, xv3.z, wk);
            wk = *(const float4*)(wb + 192);
            row_fma(acc0, xv0.w, wk); row_fma(acc1, xv1.w, wk); row_fma(acc2, xv2.w, wk); row_fma(acc3, xv3.w, wk);
        }
        __syncthreads();
#pragma unroll
        for (int i = 0; i < 4; ++i) {
            float4 o = (i == 0) ? acc0 : (i == 1) ? acc1 : (i == 2) ? acc2 : acc3;
            o.x = fmaxf(o.x, 0.f); o.y = fmaxf(o.y, 0.f); o.z = fmaxf(o.z, 0.f); o.w = fmaxf(o.w, 0.f);
            *(float4*)&Zs[tr * 4 + i][tc * 4] = o;
        }
        __syncthreads();

        // final GEMV: out[p] = Z2[p] . P2 + pb2
        {
            int p = tid >> 2, kq = tid & 3;
            float s = 0.f;
#pragma unroll
            for (int i = 0; i < 16; ++i) s = fmaf(Zs[p][kq * 16 + i], P2s[kq * 16 + i], s);
            s += __shfl_xor(s, 1, 64);
            s += __shfl_xor(s, 2, 64);
            if (kq == 0) out[base + p] = s + pb2v;
        }
    }
}

extern "C" void kernel_launch(void* const* d_in, const int* in_sizes, int n_in,
                              void* d_out, int out_size, void* d_ws, size_t ws_size,
                              hipStream_t stream) {
    const float* x     = (const float*)d_in[0];
    const float* ew    = (const float*)d_in[1];  // (3, E)
    const int* src     = (const int*)d_in[2];
    const int* dst     = (const int*)d_in[3];
    const int* pos_src = (const int*)d_in[4];
    const int* pos_dst = (const int*)d_in[5];
    const int* neg_src = (const int*)d_in[6];
    const int* neg_dst = (const int*)d_in[7];
    const float* W0    = (const float*)d_in[8];
    const float* b0    = (const float*)d_in[9];
    const float* W1    = (const float*)d_in[10];
    const float* b1    = (const float*)d_in[11];
    const float* W2    = (const float*)d_in[12];
    const float* b2    = (const float*)d_in[13];
    const float* P0    = (const float*)d_in[14];
    const float* pb0   = (const float*)d_in[15];
    const float* P1    = (const float*)d_in[16];
    const float* pb1   = (const float*)d_in[17];
    const float* P2    = (const float*)d_in[18];
    const float* pb2   = (const float*)d_in[19];
    float* out = (float*)d_out;

    float* ws = (float*)d_ws;
    float* norm_src = ws;                     // N
    float* norm_dst = ws + 100000;            // N
    int* cursor     = (int*)(ws + 200000);    // N
    int* deg_in     = (int*)(ws + 300000);    // N
    int* row_ptr    = (int*)(ws + 400000);    // N+1
    float4* cedge   = (float4*)(ws + 500004); // E
    float* hw       = ws + 4500004;           // N*64
    float* agg      = ws + 10900004;          // N*64

    int* tmp_excl  = (int*)hw;       // scan scratch (hw not yet live)
    int* blocksums = (int*)hw + NN;

    hipMemsetAsync(cursor, 0, 2 * NN * sizeof(int), stream);  // deg_out + deg_in
    deg_kernel<<<(NE / 4 + 255) / 256, 256, 0, stream>>>((const int4*)src, (const int4*)dst,
                                                         cursor, deg_in, NE / 4);
    norm_kernel<<<(NN + 255) / 256, 256, 0, stream>>>(cursor, deg_in, norm_src, norm_dst, NN);
    scan_block<<<SCAN_NB, 1024, 0, stream>>>(deg_in, tmp_excl, blocksums, NN);
    scan_sums<<<1, 128, 0, stream>>>(blocksums, SCAN_NB);
    scan_apply<<<SCAN_NB, 1024, 0, stream>>>(tmp_excl, blocksums, row_ptr, cursor, NN);
    csr_fill<<<2048, 256, 0, stream>>>(src, dst, ew, cursor, cedge, NE);

    const int NT = (NN + 63) / 64;  // 1563 tiles

    // layer 0: hw = (x @ W0) * ns   (agg epilogue produces relu(a*nd+b0)*ns)
    gemm_tile<128, true><<<NT, 256, 0, stream>>>(x, W0, norm_src, hw, NN);
    aggregate<0, false><<<4096, 256, 0, stream>>>(hw, cedge, row_ptr, norm_src, norm_dst, b0, agg, NN);
    // layer 1
    gemm_tile<64, false><<<NT, 256, 0, stream>>>(agg, W1, nullptr, hw, NN);
    aggregate<1, false><<<4096, 256, 0, stream>>>(hw, cedge, row_ptr, norm_src, norm_dst, b1, agg, NN);
    // layer 2 (final: agg <- a*nd + b2, no relu — this IS hfin)
    gemm_tile<64, false><<<NT, 256, 0, stream>>>(agg, W2, nullptr, hw, NN);
    aggregate<2, true><<<4096, 256, 0, stream>>>(hw, cedge, row_ptr, norm_src, norm_dst, b2, agg, NN);

    // MLP over pos & neg pairs
    mlp_tile<<<1024, 256, 0, stream>>>(agg, P0, pb0, P1, pb1, P2, pb2,
                                       pos_src, pos_dst, neg_src, neg_dst, out, NP);
}

// Round 7
// 484.223 us; speedup vs baseline: 1.0887x; 1.0887x over previous
//
#include <hip/hip_runtime.h>

// GCN link predictor, fp32 — round 7: de-latency-ing (round 6 was neutral: kernels
// are latency/barrier-bound, not occupancy-bound).
//  * gemm: W staged in LDS ONCE (one barrier total), X read direct from global
//    (broadcast within wave) -> zero per-tile barriers
//  * mlp: grid 3125 (one tile/block), gather phase 4x-batched (8 outstanding loads)
//  * aggregate: 8-wide batched edge loads
//
// ws layout (float units):
//   0        norm_src [N]
//   100000   norm_dst [N]
//   200000   deg_out / cursor (int) [N]
//   300000   deg_in (int) [N]
//   400000   row_ptr (int) [N+1]
//   500004   cedge (float4) [E]          (src, w_l0, w_l1, w_l2) per edge
//   4500004  hw   [N*64]   (scan scratch before layer 0)
//   10900004 agg  [N*64]
// total 17300004 floats = 69.2 MB

#define NN 100000
#define NE 1000000
#define NP 100000
#define SCAN_NB 98

__device__ __forceinline__ void row_fma(float4& acc, float xv, const float4& wv) {
    acc.x = fmaf(xv, wv.x, acc.x);
    acc.y = fmaf(xv, wv.y, acc.y);
    acc.z = fmaf(xv, wv.z, acc.z);
    acc.w = fmaf(xv, wv.w, acc.w);
}

__global__ void deg_kernel(const int4* __restrict__ src4, const int4* __restrict__ dst4,
                           int* __restrict__ deg_out, int* __restrict__ deg_in, int E4) {
    int tid = blockIdx.x * blockDim.x + threadIdx.x;
    if (tid < E4) {
        int4 s = src4[tid], d = dst4[tid];
        atomicAdd(&deg_out[s.x], 1);
        atomicAdd(&deg_out[s.y], 1);
        atomicAdd(&deg_out[s.z], 1);
        atomicAdd(&deg_out[s.w], 1);
        atomicAdd(&deg_in[d.x], 1);
        atomicAdd(&deg_in[d.y], 1);
        atomicAdd(&deg_in[d.z], 1);
        atomicAdd(&deg_in[d.w], 1);
    }
}

__global__ void norm_kernel(const int* __restrict__ deg_out, const int* __restrict__ deg_in,
                            float* __restrict__ norm_src, float* __restrict__ norm_dst, int n) {
    int i = blockIdx.x * blockDim.x + threadIdx.x;
    if (i < n) {
        norm_src[i] = rsqrtf(fmaxf((float)deg_out[i], 1.0f));
        norm_dst[i] = rsqrtf(fmaxf((float)deg_in[i], 1.0f));
    }
}

__global__ __launch_bounds__(1024) void scan_block(const int* __restrict__ deg,
                                                   int* __restrict__ tmp_excl,
                                                   int* __restrict__ blocksums, int n) {
    __shared__ int wsums[16];
    const int i = blockIdx.x * 1024 + threadIdx.x;
    const int lane = threadIdx.x & 63, w = threadIdx.x >> 6;
    int v = (i < n) ? deg[i] : 0;
    int s = v;
#pragma unroll
    for (int off = 1; off < 64; off <<= 1) {
        int u = __shfl_up(s, off, 64);
        if (lane >= off) s += u;
    }
    if (lane == 63) wsums[w] = s;
    __syncthreads();
    if (w == 0) {
        int wv = (lane < 16) ? wsums[lane] : 0;
#pragma unroll
        for (int off = 1; off < 16; off <<= 1) {
            int u = __shfl_up(wv, off, 64);
            if (lane >= off) wv += u;
        }
        if (lane < 16) wsums[lane] = wv;
    }
    __syncthreads();
    int excl = s - v + (w > 0 ? wsums[w - 1] : 0);
    if (i < n) tmp_excl[i] = excl;
    if (threadIdx.x == 1023) blocksums[blockIdx.x] = excl + v;
}

__global__ void scan_sums(int* __restrict__ bs, int nb) {
    __shared__ int wtot[2];
    const int t = threadIdx.x;  // 128 threads
    const int lane = t & 63, w = t >> 6;
    int v = (t < nb) ? bs[t] : 0;
    int s = v;
#pragma unroll
    for (int off = 1; off < 64; off <<= 1) {
        int u = __shfl_up(s, off, 64);
        if (lane >= off) s += u;
    }
    if (lane == 63) wtot[w] = s;
    __syncthreads();
    int excl = s - v + (w == 1 ? wtot[0] : 0);
    if (t < nb) bs[t] = excl;
}

__global__ __launch_bounds__(1024) void scan_apply(const int* __restrict__ tmp_excl,
                                                   const int* __restrict__ bs,
                                                   int* __restrict__ row_ptr,
                                                   int* __restrict__ cursor, int n) {
    const int i = blockIdx.x * 1024 + threadIdx.x;
    if (i < n) {
        int r = tmp_excl[i] + bs[blockIdx.x];
        row_ptr[i] = r;
        cursor[i] = r;
    }
    if (i == 0) row_ptr[n] = NE;
}

// pack each edge into its dst row: one scattered 16B write per edge.
__global__ void csr_fill(const int* __restrict__ src, const int* __restrict__ dst,
                         const float* __restrict__ ew, int* __restrict__ cursor,
                         float4* __restrict__ cedge, int E) {
    int tid = blockIdx.x * blockDim.x + threadIdx.x;
    int stride = gridDim.x * blockDim.x;
    for (int e = tid; e < E; e += stride) {
        int d = dst[e];
        int slot = atomicAdd(&cursor[d], 1);
        float4 c;
        c.x = __int_as_float(src[e]);
        c.y = ew[e];
        c.z = ew[NE + e];
        c.w = ew[2 * NE + e];
        cedge[slot] = c;
    }
}

// CSR pull aggregation, one wave per dst node, 8-wide batched loads. Fused epilogue:
//  FINAL=0: out = relu(a*norm_dst + bias)*norm_src   (input for next pure GEMM)
//  FINAL=1: out = a*norm_dst + bias                  (b2; final conv output, no relu)
template <int WSEL, bool FINAL>
__global__ __launch_bounds__(256) void aggregate(const float* __restrict__ hw,
                                                 const float4* __restrict__ cedge,
                                                 const int* __restrict__ row_ptr,
                                                 const float* __restrict__ norm_src,
                                                 const float* __restrict__ norm_dst,
                                                 const float* __restrict__ bias,
                                                 float* __restrict__ outx, int n) {
    const int lane = threadIdx.x & 63;
    const int gw = (blockIdx.x * blockDim.x + threadIdx.x) >> 6;
    const int nw = (gridDim.x * blockDim.x) >> 6;
    const float blane = bias[lane];
    for (int node = gw; node < n; node += nw) {
        int beg = row_ptr[node], end = row_ptr[node + 1];
        float a0 = 0.f, a1 = 0.f, a2 = 0.f, a3 = 0.f;
        int i = beg;
        for (; i + 7 < end; i += 8) {
            // batch 1: all 8 edge descriptors in flight
            float4 c0 = cedge[i + 0], c1 = cedge[i + 1], c2 = cedge[i + 2], c3 = cedge[i + 3];
            float4 c4 = cedge[i + 4], c5 = cedge[i + 5], c6 = cedge[i + 6], c7 = cedge[i + 7];
            // batch 2: all 8 feature-row loads in flight
            float h0 = hw[__float_as_int(c0.x) * 64 + lane];
            float h1 = hw[__float_as_int(c1.x) * 64 + lane];
            float h2 = hw[__float_as_int(c2.x) * 64 + lane];
            float h3 = hw[__float_as_int(c3.x) * 64 + lane];
            float h4 = hw[__float_as_int(c4.x) * 64 + lane];
            float h5 = hw[__float_as_int(c5.x) * 64 + lane];
            float h6 = hw[__float_as_int(c6.x) * 64 + lane];
            float h7 = hw[__float_as_int(c7.x) * 64 + lane];
            a0 = fmaf(h0, (WSEL == 0) ? c0.y : (WSEL == 1) ? c0.z : c0.w, a0);
            a1 = fmaf(h1, (WSEL == 0) ? c1.y : (WSEL == 1) ? c1.z : c1.w, a1);
            a2 = fmaf(h2, (WSEL == 0) ? c2.y : (WSEL == 1) ? c2.z : c2.w, a2);
            a3 = fmaf(h3, (WSEL == 0) ? c3.y : (WSEL == 1) ? c3.z : c3.w, a3);
            a0 = fmaf(h4, (WSEL == 0) ? c4.y : (WSEL == 1) ? c4.z : c4.w, a0);
            a1 = fmaf(h5, (WSEL == 0) ? c5.y : (WSEL == 1) ? c5.z : c5.w, a1);
            a2 = fmaf(h6, (WSEL == 0) ? c6.y : (WSEL == 1) ? c6.z : c6.w, a2);
            a3 = fmaf(h7, (WSEL == 0) ? c7.y : (WSEL == 1) ? c7.z : c7.w, a3);
        }
        for (; i + 1 < end; i += 2) {
            float4 c0 = cedge[i], c1 = cedge[i + 1];
            float h0 = hw[__float_as_int(c0.x) * 64 + lane];
            float h1 = hw[__float_as_int(c1.x) * 64 + lane];
            a0 = fmaf(h0, (WSEL == 0) ? c0.y : (WSEL == 1) ? c0.z : c0.w, a0);
            a1 = fmaf(h1, (WSEL == 0) ? c1.y : (WSEL == 1) ? c1.z : c1.w, a1);
        }
        if (i < end) {
            float4 c0 = cedge[i];
            float h0 = hw[__float_as_int(c0.x) * 64 + lane];
            a0 = fmaf(h0, (WSEL == 0) ? c0.y : (WSEL == 1) ? c0.z : c0.w, a0);
        }
        float a = (a0 + a1) + (a2 + a3);
        float nd = norm_dst[node];
        float t;
        if (FINAL) {
            t = fmaf(a, nd, blane);
        } else {
            t = fmaxf(fmaf(a, nd, blane), 0.f) * norm_src[node];
        }
        outx[node * 64 + lane] = t;
    }
}

// 64-row GEMM tile, W in LDS (staged once), X direct from global (wave-broadcast).
// No per-tile barriers. out[row][j] = (SCALE ? norm_src[row] : 1) * sum_k in[row][k]*W[k][j]
template <int K, bool SCALE>
__global__ __launch_bounds__(256, 5) void gemm_tile(const float* __restrict__ in,
                                                    const float* __restrict__ W,
                                                    const float* __restrict__ norm_src,
                                                    float* __restrict__ out, int n) {
    __shared__ float Ws[K * 64];
    const int tid = threadIdx.x;
    for (int i = tid; i < K * 16; i += 256) ((float4*)Ws)[i] = ((const float4*)W)[i];
    __syncthreads();  // the only barrier in the kernel

    const int tr = tid >> 4, tc = tid & 15;
    const int row0 = blockIdx.x * 64 + tr * 4;
    const float* xr0 = in + (size_t)min(row0 + 0, n - 1) * K;
    const float* xr1 = in + (size_t)min(row0 + 1, n - 1) * K;
    const float* xr2 = in + (size_t)min(row0 + 2, n - 1) * K;
    const float* xr3 = in + (size_t)min(row0 + 3, n - 1) * K;

    float4 acc0 = {0, 0, 0, 0}, acc1 = {0, 0, 0, 0}, acc2 = {0, 0, 0, 0}, acc3 = {0, 0, 0, 0};
#pragma unroll 4
    for (int k4 = 0; k4 < K / 4; ++k4) {
        const int kb = k4 * 4;
        float4 xv0 = *(const float4*)&xr0[kb];
        float4 xv1 = *(const float4*)&xr1[kb];
        float4 xv2 = *(const float4*)&xr2[kb];
        float4 xv3 = *(const float4*)&xr3[kb];
        const float* wb = &Ws[kb * 64 + tc * 4];
        float4 wk;
        wk = *(const float4*)(wb);
        row_fma(acc0, xv0.x, wk); row_fma(acc1, xv1.x, wk); row_fma(acc2, xv2.x, wk); row_fma(acc3, xv3.x, wk);
        wk = *(const float4*)(wb + 64);
        row_fma(acc0, xv0.y, wk); row_fma(acc1, xv1.y, wk); row_fma(acc2, xv2.y, wk); row_fma(acc3, xv3.y, wk);
        wk = *(const float4*)(wb + 128);
        row_fma(acc0, xv0.z, wk); row_fma(acc1, xv1.z, wk); row_fma(acc2, xv2.z, wk); row_fma(acc3, xv3.z, wk);
        wk = *(const float4*)(wb + 192);
        row_fma(acc0, xv0.w, wk); row_fma(acc1, xv1.w, wk); row_fma(acc2, xv2.w, wk); row_fma(acc3, xv3.w, wk);
    }

#pragma unroll
    for (int i = 0; i < 4; ++i) {
        int row = row0 + i;
        if (row < n) {
            float4 o = (i == 0) ? acc0 : (i == 1) ? acc1 : (i == 2) ? acc2 : acc3;
            if (SCALE) {
                float ns = norm_src[row];
                o.x *= ns; o.y *= ns; o.z *= ns; o.w *= ns;
            }
            *(float4*)&out[row * 64 + tc * 4] = o;
        }
    }
}

#define ZST 76  // Zs row stride (x4B = 304B, 16B-aligned)

// 64 pairs per block (grid = 3125): Z staged in LDS, P0/P1 from global (L1-broadcast).
__global__ __launch_bounds__(256) void mlp_tile(const float* __restrict__ hfin,
                                                const float* __restrict__ P0,
                                                const float* __restrict__ pb0,
                                                const float* __restrict__ P1,
                                                const float* __restrict__ pb1,
                                                const float* __restrict__ P2,
                                                const float* __restrict__ pb2,
                                                const int* __restrict__ pos_src,
                                                const int* __restrict__ pos_dst,
                                                const int* __restrict__ neg_src,
                                                const int* __restrict__ neg_dst,
                                                float* __restrict__ out, int P) {
    __shared__ float Zs[64][ZST];
    __shared__ float pb0s[64], pb1s[64], P2s[64];
    __shared__ int pas[64], pbs[64];
    const int tid = threadIdx.x;
    const int base = blockIdx.x << 6;
    if (tid < 64) {
        pb0s[tid] = pb0[tid];
        pb1s[tid] = pb1[tid];
        P2s[tid] = P2[tid];
        int p = base + tid;
        pas[tid] = (p < P) ? pos_src[p] : neg_src[p - P];
        pbs[tid] = (p < P) ? pos_dst[p] : neg_dst[p - P];
    }
    const float pb2v = pb2[0];
    const int lane = tid & 63, w = tid >> 6;
    const int tr = tid >> 4, tc = tid & 15;
    __syncthreads();

    // gather + product, 4x-batched: 8 row-loads in flight per round
    {
        const int p0 = 0 + w, p1 = 4 + w, p2 = 8 + w, p3 = 12 + w;
#pragma unroll
        for (int pb = 0; pb < 64; pb += 16) {
            int a0 = pas[pb + p0], b0 = pbs[pb + p0];
            int a1 = pas[pb + p1], b1 = pbs[pb + p1];
            int a2 = pas[pb + p2], b2 = pbs[pb + p2];
            int a3 = pas[pb + p3], b3 = pbs[pb + p3];
            float ha0 = hfin[a0 * 64 + lane], hb0 = hfin[b0 * 64 + lane];
            float ha1 = hfin[a1 * 64 + lane], hb1 = hfin[b1 * 64 + lane];
            float ha2 = hfin[a2 * 64 + lane], hb2 = hfin[b2 * 64 + lane];
            float ha3 = hfin[a3 * 64 + lane], hb3 = hfin[b3 * 64 + lane];
            Zs[pb + p0][lane] = ha0 * hb0;
            Zs[pb + p1][lane] = ha1 * hb1;
            Zs[pb + p2][lane] = ha2 * hb2;
            Zs[pb + p3][lane] = ha3 * hb3;
        }
    }
    __syncthreads();

    // layer 0: Z1 = relu(Z @ P0 + pb0)
    float4 acc0, acc1, acc2, acc3;
    {
        float4 binit = *(const float4*)&pb0s[tc * 4];
        acc0 = binit; acc1 = binit; acc2 = binit; acc3 = binit;
    }
#pragma unroll 4
    for (int k4 = 0; k4 < 16; ++k4) {
        const int kb = k4 * 4;
        float4 xv0 = *(const float4*)&Zs[tr * 4 + 0][kb];
        float4 xv1 = *(const float4*)&Zs[tr * 4 + 1][kb];
        float4 xv2 = *(const float4*)&Zs[tr * 4 + 2][kb];
        float4 xv3 = *(const float4*)&Zs[tr * 4 + 3][kb];
        const float* wb = &P0[kb * 64 + tc * 4];
        float4 wk;
        wk = *(const float4*)(wb);
        row_fma(acc0, xv0.x, wk); row_fma(acc1, xv1.x, wk); row_fma(acc2, xv2.x, wk); row_fma(acc3, xv3.x, wk);
        wk = *(const float4*)(wb + 64);
        row_fma(acc0, xv0.y, wk); row_fma(acc1, xv1.y, wk); row_fma(acc2, xv2.y, wk); row_fma(acc3, xv3.y, wk);
        wk = *(const float4*)(wb + 128);
        row_fma(acc0, xv0.z, wk); row_fma(acc1, xv1.z, wk); row_fma(acc2, xv2.z, wk); row_fma(acc3, xv3.z, wk);
        wk = *(const float4*)(wb + 192);
        row_fma(acc0, xv0.w, wk); row_fma(acc1, xv1.w, wk); row_fma(acc2, xv2.w, wk); row_fma(acc3, xv3.w, wk);
    }
    __syncthreads();
#pragma unroll
    for (int i = 0; i < 4; ++i) {
        float4 o = (i == 0) ? acc0 : (i == 1) ? acc1 : (i == 2) ? acc2 : acc3;
        o.x = fmaxf(o.x, 0.f); o.y = fmaxf(o.y, 0.f); o.z = fmaxf(o.z, 0.f); o.w = fmaxf(o.w, 0.f);
        *(float4*)&Zs[tr * 4 + i][tc * 4] = o;
    }
    __syncthreads();

    // layer 1: Z2 = relu(Z1 @ P1 + pb1)
    {
        float4 binit = *(const float4*)&pb1s[tc * 4];
        acc0 = binit; acc1 = binit; acc2 = binit; acc3 = binit;
    }
#pragma unroll 4
    for (int k4 = 0; k4 < 16; ++k4) {
        const int kb = k4 * 4;
        float4 xv0 = *(const float4*)&Zs[tr * 4 + 0][kb];
        float4 xv1 = *(const float4*)&Zs[tr * 4 + 1][kb];
        float4 xv2 = *(const float4*)&Zs[tr * 4 + 2][kb];
        float4 xv3 = *(const float4*)&Zs[tr * 4 + 3][kb];
        const float* wb = &P1[kb * 64 + tc * 4];
        float4 wk;
        wk = *(const float4*)(wb);
        row_fma(acc0, xv0.x, wk); row_fma(acc1, xv1.x, wk); row_fma(acc2, xv2.x, wk); row_fma(acc3, xv3.x, wk);
        wk = *(const float4*)(wb + 64);
        row_fma(acc0, xv0.y, wk); row_fma(acc1, xv1.y, wk); row_fma(acc2, xv2.y, wk); row_fma(acc3, xv3.y, wk);
        wk = *(const float4*)(wb + 128);
        row_fma(acc0, xv0.z, wk); row_fma(acc1, xv1.z, wk); row_fma(acc2, xv2.z, wk); row_fma(acc3, xv3.z, wk);
        wk = *(const float4*)(wb + 192);
        row_fma(acc0, xv0.w, wk); row_fma(acc1, xv1.w, wk); row_fma(acc2, xv2.w, wk); row_fma(acc3, xv3.w, wk);
    }
    __syncthreads();
#pragma unroll
    for (int i = 0; i < 4; ++i) {
        float4 o = (i == 0) ? acc0 : (i == 1) ? acc1 : (i == 2) ? acc2 : acc3;
        o.x = fmaxf(o.x, 0.f); o.y = fmaxf(o.y, 0.f); o.z = fmaxf(o.z, 0.f); o.w = fmaxf(o.w, 0.f);
        *(float4*)&Zs[tr * 4 + i][tc * 4] = o;
    }
    __syncthreads();

    // final GEMV: out[p] = Z2[p] . P2 + pb2
    {
        int p = tid >> 2, kq = tid & 3;
        float s = 0.f;
#pragma unroll
        for (int i = 0; i < 16; ++i) s = fmaf(Zs[p][kq * 16 + i], P2s[kq * 16 + i], s);
        s += __shfl_xor(s, 1, 64);
        s += __shfl_xor(s, 2, 64);
        if (kq == 0) out[base + p] = s + pb2v;
    }
}

extern "C" void kernel_launch(void* const* d_in, const int* in_sizes, int n_in,
                              void* d_out, int out_size, void* d_ws, size_t ws_size,
                              hipStream_t stream) {
    const float* x     = (const float*)d_in[0];
    const float* ew    = (const float*)d_in[1];  // (3, E)
    const int* src     = (const int*)d_in[2];
    const int* dst     = (const int*)d_in[3];
    const int* pos_src = (const int*)d_in[4];
    const int* pos_dst = (const int*)d_in[5];
    const int* neg_src = (const int*)d_in[6];
    const int* neg_dst = (const int*)d_in[7];
    const float* W0    = (const float*)d_in[8];
    const float* b0    = (const float*)d_in[9];
    const float* W1    = (const float*)d_in[10];
    const float* b1    = (const float*)d_in[11];
    const float* W2    = (const float*)d_in[12];
    const float* b2    = (const float*)d_in[13];
    const float* P0    = (const float*)d_in[14];
    const float* pb0   = (const float*)d_in[15];
    const float* P1    = (const float*)d_in[16];
    const float* pb1   = (const float*)d_in[17];
    const float* P2    = (const float*)d_in[18];
    const float* pb2   = (const float*)d_in[19];
    float* out = (float*)d_out;

    float* ws = (float*)d_ws;
    float* norm_src = ws;                     // N
    float* norm_dst = ws + 100000;            // N
    int* cursor     = (int*)(ws + 200000);    // N
    int* deg_in     = (int*)(ws + 300000);    // N
    int* row_ptr    = (int*)(ws + 400000);    // N+1
    float4* cedge   = (float4*)(ws + 500004); // E
    float* hw       = ws + 4500004;           // N*64
    float* agg      = ws + 10900004;          // N*64

    int* tmp_excl  = (int*)hw;       // scan scratch (hw not yet live)
    int* blocksums = (int*)hw + NN;

    hipMemsetAsync(cursor, 0, 2 * NN * sizeof(int), stream);  // deg_out + deg_in
    deg_kernel<<<(NE / 4 + 255) / 256, 256, 0, stream>>>((const int4*)src, (const int4*)dst,
                                                         cursor, deg_in, NE / 4);
    norm_kernel<<<(NN + 255) / 256, 256, 0, stream>>>(cursor, deg_in, norm_src, norm_dst, NN);
    scan_block<<<SCAN_NB, 1024, 0, stream>>>(deg_in, tmp_excl, blocksums, NN);
    scan_sums<<<1, 128, 0, stream>>>(blocksums, SCAN_NB);
    scan_apply<<<SCAN_NB, 1024, 0, stream>>>(tmp_excl, blocksums, row_ptr, cursor, NN);
    csr_fill<<<2048, 256, 0, stream>>>(src, dst, ew, cursor, cedge, NE);

    const int NT = (NN + 63) / 64;  // 1563 tiles

    // layer 0: hw = (x @ W0) * ns   (agg epilogue produces relu(a*nd+b0)*ns)
    gemm_tile<128, true><<<NT, 256, 0, stream>>>(x, W0, norm_src, hw, NN);
    aggregate<0, false><<<4096, 256, 0, stream>>>(hw, cedge, row_ptr, norm_src, norm_dst, b0, agg, NN);
    // layer 1
    gemm_tile<64, false><<<NT, 256, 0, stream>>>(agg, W1, nullptr, hw, NN);
    aggregate<1, false><<<4096, 256, 0, stream>>>(hw, cedge, row_ptr, norm_src, norm_dst, b1, agg, NN);
    // layer 2 (final: agg <- a*nd + b2, no relu — this IS hfin)
    gemm_tile<64, false><<<NT, 256, 0, stream>>>(agg, W2, nullptr, hw, NN);
    aggregate<2, true><<<4096, 256, 0, stream>>>(hw, cedge, row_ptr, norm_src, norm_dst, b2, agg, NN);

    // MLP over pos & neg pairs (grid = exactly one 64-pair tile per block)
    mlp_tile<<<(2 * NP) / 64, 256, 0, stream>>>(agg, P0, pb0, P1, pb1, P2, pb2,
                                                pos_src, pos_dst, neg_src, neg_dst, out, NP);
}